// Round 3
// baseline (806.172 us; speedup 1.0000x reference)
//
#include <hip/hip_runtime.h>
#include <math.h>

typedef unsigned short u16;
typedef unsigned int u32;
typedef __attribute__((ext_vector_type(4))) unsigned short u16x4;
typedef __attribute__((ext_vector_type(8))) short bf16x8;
typedef __attribute__((ext_vector_type(4))) float f32x4;

#define B_ 4
#define S_ 2048
#define D_ 1024
#define H_ 16
#define NT (B_*S_)
#define DFF 4096

static __device__ __forceinline__ float bf2f(u16 u) {
    return __uint_as_float(((u32)u) << 16);
}
static __device__ __forceinline__ u16 f2bf(float f) {
    u32 u = __float_as_uint(f);
    u32 r = (u + 0x7fffu + ((u >> 16) & 1u)) >> 16;
    return (u16)r;
}
// async 16B/lane global->LDS (LDS dest = wave-uniform base + lane*16)
static __device__ __forceinline__ void gload_lds16(const void* g, void* l) {
    __builtin_amdgcn_global_load_lds(
        (const __attribute__((address_space(1))) void*)g,
        (__attribute__((address_space(3))) void*)l, 16, 0, 0);
}

// ------------------------------------------------- transpose fp32 -> bf16
__global__ void transpose_f2b4(const float* __restrict__ s0, const float* __restrict__ s1,
                               const float* __restrict__ s2, const float* __restrict__ s3,
                               u16* __restrict__ d0, u16* __restrict__ d1,
                               u16* __restrict__ d2, u16* __restrict__ d3,
                               int R, int C) {
    const float* in = s0; u16* out = d0;
    if (blockIdx.z == 1) { in = s1; out = d1; }
    else if (blockIdx.z == 2) { in = s2; out = d2; }
    else if (blockIdx.z == 3) { in = s3; out = d3; }
    __shared__ float t[32][33];
    int c0 = blockIdx.x * 32, r0 = blockIdx.y * 32;
    int x = threadIdx.x, y = threadIdx.y;
    #pragma unroll
    for (int i = 0; i < 4; i++)
        t[y + i*8][x] = in[(long)(r0 + y + i*8) * C + c0 + x];
    __syncthreads();
    #pragma unroll
    for (int i = 0; i < 4; i++)
        out[(long)(c0 + y + i*8) * R + r0 + x] = f2bf(t[x][y + i*8]);
}

__global__ void transpose_f2b(const float* __restrict__ in, u16* __restrict__ out,
                              int R, int C) {
    __shared__ float t[32][33];
    int c0 = blockIdx.x * 32, r0 = blockIdx.y * 32;
    int x = threadIdx.x, y = threadIdx.y;
    #pragma unroll
    for (int i = 0; i < 4; i++)
        t[y + i*8][x] = in[(long)(r0 + y + i*8) * C + c0 + x];
    __syncthreads();
    #pragma unroll
    for (int i = 0; i < 4; i++)
        out[(long)(c0 + y + i*8) * R + r0 + x] = f2bf(t[x][y + i*8]);
}

// V bf16 [B*S][D] -> Vt bf16 [B*H][64][S]. grid (S/32, 2, B*H), block (32,8)
__global__ void transpose_v(const u16* __restrict__ V, u16* __restrict__ Vt) {
    __shared__ u16 t[32][33];
    int z = blockIdx.z; int b = z >> 4, h = z & 15;
    int s0 = blockIdx.x * 32, d0 = blockIdx.y * 32;
    int x = threadIdx.x, y = threadIdx.y;
    const u16* in = V + ((long)b * S_ + s0) * D_ + h * 64 + d0;
    #pragma unroll
    for (int i = 0; i < 4; i++)
        t[y + i*8][x] = in[(long)(y + i*8) * D_ + x];
    __syncthreads();
    u16* out = Vt + ((long)z * 64 + d0) * S_ + s0;
    #pragma unroll
    for (int i = 0; i < 4; i++)
        out[(long)(y + i*8) * S_ + x] = t[x][y + i*8];
}

// ------------------------------------------------- layernorm (fp32 in, bf16 out)
__global__ __launch_bounds__(256) void ln_kernel(
    const float* __restrict__ X, const float* __restrict__ alpha,
    const float* __restrict__ beta, u16* __restrict__ Y) {
    int row = blockIdx.x, tid = threadIdx.x;
    float4 xv = ((const float4*)(X + (long)row * D_))[tid];
    float v[4] = {xv.x, xv.y, xv.z, xv.w};
    float s = 0.f, ss = 0.f;
    #pragma unroll
    for (int i = 0; i < 4; i++) { s += v[i]; ss += v[i]*v[i]; }
    #pragma unroll
    for (int off = 32; off >= 1; off >>= 1) {
        s += __shfl_xor(s, off);
        ss += __shfl_xor(ss, off);
    }
    __shared__ float red[8];
    __shared__ float stats[2];
    int w = tid >> 6;
    if ((tid & 63) == 0) { red[w] = s; red[4 + w] = ss; }
    __syncthreads();
    if (tid == 0) {
        float S = red[0] + red[1] + red[2] + red[3];
        float SS = red[4] + red[5] + red[6] + red[7];
        float mean = S * (1.f / D_);
        float var = SS * (1.f / D_) - mean * mean;
        stats[0] = mean; stats[1] = rsqrtf(var + 1e-5f);
    }
    __syncthreads();
    float mean = stats[0], rstd = stats[1];
    float4 av = ((const float4*)alpha)[tid];
    float4 bv = ((const float4*)beta)[tid];
    u16x4 o;
    o[0] = f2bf((v[0] - mean) * rstd * av.x + bv.x);
    o[1] = f2bf((v[1] - mean) * rstd * av.y + bv.y);
    o[2] = f2bf((v[2] - mean) * rstd * av.z + bv.z);
    o[3] = f2bf((v[3] - mean) * rstd * av.w + bv.w);
    *(u16x4*)(Y + (long)row * D_ + tid * 4) = o;
}

// ------------------------------------------------- GEMM (bf16 A, bf16 B^T)
// R10: 2-phase double-buffered pipeline (T3 minimum recipe). Old structure
// exposed the full global->LDS latency per K-step (stage -> vmcnt(0) drain at
// barrier -> compute); now next tile's global_load_lds is issued BEFORE the
// current tile's MFMAs, one barrier per K-step (its implicit vmcnt(0) drains
// loads that have had a compute-phase to land). LDS 64 KB -> 2 blocks/CU.
// Also: XCD-chunked bijective block swizzle (all grids have nwg%8==0).
#define BM 128
#define BN 128
#define BK 64

static __device__ __forceinline__ void mfma_tile(
    const u16* As, const u16* Bs, f32x4 (&acc)[4][4],
    int wm, int wn, int l15, int quad) {
    #pragma unroll
    for (int ks = 0; ks < 2; ks++) {
        bf16x8 af[4], bfm[4];
        #pragma unroll
        for (int mt = 0; mt < 4; mt++)
            af[mt] = *(const bf16x8*)&As[(wm*64 + mt*16 + l15) * BK + ks*32 + quad*8];
        #pragma unroll
        for (int nt = 0; nt < 4; nt++)
            bfm[nt] = *(const bf16x8*)&Bs[(wn*64 + nt*16 + l15) * BK + ks*32 + quad*8];
        #pragma unroll
        for (int mt = 0; mt < 4; mt++)
            #pragma unroll
            for (int nt = 0; nt < 4; nt++)
                acc[mt][nt] = __builtin_amdgcn_mfma_f32_16x16x32_bf16(
                    af[mt], bfm[nt], acc[mt][nt], 0, 0, 0);
    }
}

__global__ __launch_bounds__(256, 2) void gemm_bt(
    const u16* __restrict__ A,
    const u16* __restrict__ Bt0, const u16* __restrict__ Bt1, const u16* __restrict__ Bt2,
    void* __restrict__ C0, void* __restrict__ C1, void* __restrict__ C2,
    int M, int N, int K, int mode,
    const float* __restrict__ bias, const float* __restrict__ resid) {
    const u16* Bt = Bt0; void* C = C0;
    if (blockIdx.z == 1) { Bt = Bt1; C = C1; }
    else if (blockIdx.z == 2) { Bt = Bt2; C = C2; }

    __shared__ __align__(16) u16 Asm[2][BM * BK];
    __shared__ __align__(16) u16 Bsm[2][BN * BK];

    int tid = threadIdx.x;
    int lane = tid & 63, wave = tid >> 6;
    int l15 = lane & 15, quad = lane >> 4;
    int wm = wave & 1, wn = wave >> 1;

    // XCD-chunked bijective swizzle: dispatch order round-robins XCDs, so
    // giving XCD x the contiguous chunk [x*nwg/8, (x+1)*nwg/8) keeps
    // neighboring output tiles (sharing A/B panels) on one XCD's L2.
    int nx = gridDim.x;
    int nwg = nx * gridDim.y;
    int orig = blockIdx.y * nx + blockIdx.x;
    int wgid = (orig & 7) * (nwg >> 3) + (orig >> 3);
    int bx = wgid % nx, by = wgid / nx;
    long tm0 = (long)by * BM, tn0 = (long)bx * BN;

    int srow = lane >> 3;
    int scol = (lane & 7) * 8;

    const u16* aB[4]; const u16* bB[4];
    #pragma unroll
    for (int c = 0; c < 4; c++) {
        int row = (wave * 4 + c) * 8 + srow;
        aB[c] = A  + (tm0 + row) * (long)K + scol;
        bB[c] = Bt + (tn0 + row) * (long)K + scol;
    }

    f32x4 acc[4][4] = {};

    // prologue: stage tile 0 into buf 0
    #pragma unroll
    for (int c = 0; c < 4; c++) {
        int chunk = wave * 4 + c;
        gload_lds16(aB[c], &Asm[0][chunk * 512]);
        gload_lds16(bB[c], &Bsm[0][chunk * 512]);
    }
    __syncthreads();

    int steps = K / BK;
    for (int k = 0; k < steps - 1; k++) {
        int nb = (k + 1) & 1;
        long koff = (long)(k + 1) * BK;
        // issue next-tile loads first -> latency hides under this tile's MFMAs
        #pragma unroll
        for (int c = 0; c < 4; c++) {
            int chunk = wave * 4 + c;
            gload_lds16(aB[c] + koff, &Asm[nb][chunk * 512]);
            gload_lds16(bB[c] + koff, &Bsm[nb][chunk * 512]);
        }
        mfma_tile(&Asm[k & 1][0], &Bsm[k & 1][0], acc, wm, wn, l15, quad);
        __syncthreads();   // implicit vmcnt(0)+lgkmcnt(0) drain, then barrier
    }
    mfma_tile(&Asm[(steps - 1) & 1][0], &Bsm[(steps - 1) & 1][0], acc, wm, wn, l15, quad);

    #pragma unroll
    for (int mt = 0; mt < 4; mt++) {
        #pragma unroll
        for (int nt = 0; nt < 4; nt++) {
            #pragma unroll
            for (int i = 0; i < 4; i++) {
                long r = tm0 + wm*64 + mt*16 + quad*4 + i;
                long cn = tn0 + wn*64 + nt*16 + l15;
                long idx = r * N + cn;
                float val = acc[mt][nt][i];
                if (mode == 0) {
                    ((u16*)C)[idx] = f2bf(val);
                } else if (mode == 1) {
                    ((float*)C)[idx] = val + resid[idx];
                } else if (mode == 2) {
                    val += bias[cn];
                    val = 0.5f * val * (1.0f + erff(val * 0.70710678118654752f));
                    ((u16*)C)[idx] = f2bf(val);
                } else {
                    ((float*)C)[idx] = val + bias[cn] + resid[idx];
                }
            }
        }
    }
}

// ------------------------------------------------- attention
// R10: split-K across wave pairs. The fixed-max (MMAX) exp2 softmax makes
// partial o / lacc EXACTLY additive over k-tiles (no rescale), so each
// q-tile pair j/(63-j) is computed by TWO waves: wave hk takes k-tiles
// kt = hk, hk+2, ... (partition, not duplication -> same total loads/VALU/
// MFMA). Grid (64,16) -> 1024 blocks = 4 blocks/CU = 16 waves/CU (was 2
// blocks/CU, grid-limited, MfmaUtil 8.6 / VALUBusy 28 both latency-idle).
// Merge = 2 barriers + LDS add per tile. Head->XCD L2 locality preserved:
// linear dispatch id = x + 64*y, %8 = x%8, all blocks of a head same XCD.
#define LDP 72   // P row stride in u16

__global__ __launch_bounds__(256, 4) void attn_kernel(
    const u16* __restrict__ Q, const u16* __restrict__ Kg, const u16* __restrict__ Vt,
    const int* __restrict__ mask, u16* __restrict__ O) {
    __shared__ __align__(16) u16 Psm[4][32 * LDP];
    __shared__ __align__(16) float Mrg[2][64][40];   // partial o(32)+lacc(8) per lane
    int tid = threadIdx.x;
    int lane = tid & 63, wave = tid >> 6;
    int l15 = lane & 15, quad = lane >> 4;
    int bh = blockIdx.x; int b = bh >> 4, h = bh & 15;
    int pslot = wave >> 1;              // pair slot within block (0..1)
    int hk = wave & 1;                  // k-range half (even/odd k-tiles)
    int j = blockIdx.y * 2 + pslot;     // pair index 0..31
    long tokBase = (long)b * S_;
    const float SCL = 0.125f * 1.4426950408889634f;  // exp2 domain
    const float MMAX = 20.0f;                        // fixed softmax shift

    const bf16x8 ones = {16256,16256,16256,16256,16256,16256,16256,16256}; // bf16 1.0
    u16* Pw = Psm[wave];
    const int* mb = mask + b * S_;

    #pragma unroll
    for (int half = 0; half < 2; half++) {
        int t = half ? (63 - j) : j;   // q-tile index 0..63
        int q0 = t * 32;

        bf16x8 aq[2][2];
        #pragma unroll
        for (int mt = 0; mt < 2; mt++) {
            const u16* qptr = Q + (tokBase + q0 + mt*16 + l15) * D_ + h * 64;
            aq[mt][0] = *(const bf16x8*)(qptr + quad * 8);
            aq[mt][1] = *(const bf16x8*)(qptr + 32 + quad * 8);
        }

        f32x4 o[2][4] = {};
        f32x4 lacc[2] = {};
        int ktiles = t / 2 + 1;

        for (int kt = hk; kt < ktiles; kt += 2) {
            int k0 = kt * 64;
            bf16x8 kb[4][2], vb[4][2];
            #pragma unroll
            for (int nt = 0; nt < 4; nt++) {
                const u16* kp = Kg + (tokBase + k0 + nt*16 + l15) * D_ + h * 64;
                kb[nt][0] = *(const bf16x8*)(kp + quad * 8);
                kb[nt][1] = *(const bf16x8*)(kp + 32 + quad * 8);
            }
            #pragma unroll
            for (int d = 0; d < 4; d++) {
                const u16* vp = Vt + ((long)bh * 64 + d*16 + l15) * S_ + k0;
                vb[d][0] = *(const bf16x8*)(vp + quad * 8);
                vb[d][1] = *(const bf16x8*)(vp + 32 + quad * 8);
            }

            f32x4 s[2][4] = {};
            #pragma unroll
            for (int nt = 0; nt < 4; nt++) {
                s[0][nt] = __builtin_amdgcn_mfma_f32_16x16x32_bf16(aq[0][0], kb[nt][0], s[0][nt], 0,0,0);
                s[0][nt] = __builtin_amdgcn_mfma_f32_16x16x32_bf16(aq[0][1], kb[nt][1], s[0][nt], 0,0,0);
                s[1][nt] = __builtin_amdgcn_mfma_f32_16x16x32_bf16(aq[1][0], kb[nt][0], s[1][nt], 0,0,0);
                s[1][nt] = __builtin_amdgcn_mfma_f32_16x16x32_bf16(aq[1][1], kb[nt][1], s[1][nt], 0,0,0);
            }

            int mk = 0;
            #pragma unroll
            for (int nt = 0; nt < 4; nt++)
                if (mb[k0 + nt*16 + l15] != 0) mk |= (1 << nt);

            #pragma unroll
            for (int mt = 0; mt < 2; mt++) {
                #pragma unroll
                for (int i = 0; i < 4; i++) {
                    int qq = q0 + mt*16 + quad*4 + i;
                    #pragma unroll
                    for (int nt = 0; nt < 4; nt++) {
                        int kc = k0 + nt*16 + l15;
                        float p = exp2f(fmaf(s[mt][nt][i], SCL, -MMAX));
                        p = (kc <= qq && ((mk >> nt) & 1)) ? p : 0.f;
                        Pw[(mt*16 + quad*4 + i) * LDP + nt*16 + l15] = f2bf(p);
                    }
                }
            }
            // same-wave P write -> read ordering (P is wave-private)
            asm volatile("s_waitcnt lgkmcnt(0)" ::: "memory");

            #pragma unroll
            for (int hv = 0; hv < 2; hv++) {
                bf16x8 ap0 = *(const bf16x8*)&Pw[l15 * LDP + hv*32 + quad*8];
                bf16x8 ap1 = *(const bf16x8*)&Pw[(16 + l15) * LDP + hv*32 + quad*8];
                #pragma unroll
                for (int d = 0; d < 4; d++) {
                    o[0][d] = __builtin_amdgcn_mfma_f32_16x16x32_bf16(ap0, vb[d][hv], o[0][d], 0,0,0);
                    o[1][d] = __builtin_amdgcn_mfma_f32_16x16x32_bf16(ap1, vb[d][hv], o[1][d], 0,0,0);
                }
                lacc[0] = __builtin_amdgcn_mfma_f32_16x16x32_bf16(ap0, ones, lacc[0], 0,0,0);
                lacc[1] = __builtin_amdgcn_mfma_f32_16x16x32_bf16(ap1, ones, lacc[1], 0,0,0);
            }
        }

        // merge the two k-halves (partials are additive: fixed MMAX, no rescale)
        if (hk == 1) {
            float* m = &Mrg[pslot][lane][0];
            #pragma unroll
            for (int mt = 0; mt < 2; mt++)
                #pragma unroll
                for (int d = 0; d < 4; d++)
                    *(f32x4*)&m[(mt*4 + d)*4] = o[mt][d];
            *(f32x4*)&m[32] = lacc[0];
            *(f32x4*)&m[36] = lacc[1];
        }
        __syncthreads();
        if (hk == 0) {
            const float* m = &Mrg[pslot][lane][0];
            #pragma unroll
            for (int mt = 0; mt < 2; mt++)
                #pragma unroll
                for (int d = 0; d < 4; d++)
                    o[mt][d] += *(const f32x4*)&m[(mt*4 + d)*4];
            lacc[0] += *(const f32x4*)&m[32];
            lacc[1] += *(const f32x4*)&m[36];

            #pragma unroll
            for (int mt = 0; mt < 2; mt++) {
                #pragma unroll
                for (int i = 0; i < 4; i++) {
                    float inv = 1.f / lacc[mt][i];
                    long r = tokBase + q0 + mt*16 + quad*4 + i;
                    #pragma unroll
                    for (int d = 0; d < 4; d++)
                        O[r * D_ + h*64 + d*16 + l15] = f2bf(o[mt][d][i] * inv);
                }
            }
        }
        __syncthreads();   // protect Mrg reuse by next tile
    }
}

// ------------------------------------------------- launch
extern "C" void kernel_launch(void* const* d_in, const int* in_sizes, int n_in,
                              void* d_out, int out_size, void* d_ws, size_t ws_size,
                              hipStream_t stream) {
    const float* x    = (const float*)d_in[0];
    const int*   am   = (const int*)d_in[1];
    const float* ln1a = (const float*)d_in[2];
    const float* ln1b = (const float*)d_in[3];
    const float* ln2a = (const float*)d_in[4];
    const float* ln2b = (const float*)d_in[5];
    const float* wq   = (const float*)d_in[6];
    const float* wk   = (const float*)d_in[7];
    const float* wv   = (const float*)d_in[8];
    const float* wo   = (const float*)d_in[9];
    const float* w1   = (const float*)d_in[10];
    const float* b1   = (const float*)d_in[11];
    const float* w2   = (const float*)d_in[12];
    const float* b2   = (const float*)d_in[13];
    float* out = (float*)d_out;

    // Workspace: 72 MB, liveness-overlapped 16MB slots.
    char* ws = (char*)d_ws;
    const size_t MB16 = (size_t)16 * 1024 * 1024;
    u16* y1      = (u16*)(ws + 0 * MB16);
    u16* q       = (u16*)(ws + 1 * MB16);
    u16* k       = (u16*)(ws + 2 * MB16);
    u16* v       = (u16*)(ws + 3 * MB16);
    u16* wqt     = (u16*)(ws + 4 * MB16 + 0 * (size_t)D_ * D_ * 2);
    u16* wkt     = (u16*)(ws + 4 * MB16 + 1 * (size_t)D_ * D_ * 2);
    u16* wvt     = (u16*)(ws + 4 * MB16 + 2 * (size_t)D_ * D_ * 2);
    u16* wot     = (u16*)(ws + 4 * MB16 + 3 * (size_t)D_ * D_ * 2);
    u16* y2      = y1;
    u16* w1t     = q;
    u16* w2t     = q + (size_t)D_ * DFF;
    u16* h_full  = k;
    u16* ctx     = v;
    u16*   vt  = (u16*)d_out;                // d_out scratch; dead after attn
    float* x1f = out;

    dim3 tb(32, 8);
    transpose_f2b4<<<dim3(D_/32, D_/32, 4), tb, 0, stream>>>(
        wq, wk, wv, wo, wqt, wkt, wvt, wot, D_, D_);

    ln_kernel<<<NT, 256, 0, stream>>>(x, ln1a, ln1b, y1);

    gemm_bt<<<dim3(D_/BN, NT/BM, 3), 256, 0, stream>>>(
        y1, wqt, wkt, wvt, q, k, v, NT, D_, D_, 0, nullptr, nullptr);

    transpose_v<<<dim3(S_/32, 2, B_*H_), tb, 0, stream>>>(v, vt);

    attn_kernel<<<dim3(B_*H_, 16), 256, 0, stream>>>(q, k, vt, am, ctx);

    gemm_bt<<<dim3(D_/BN, NT/BM, 1), 256, 0, stream>>>(
        ctx, wot, wot, wot, x1f, x1f, x1f, NT, D_, D_, 1, nullptr, x);

    transpose_f2b<<<dim3(DFF/32, D_/32), tb, 0, stream>>>(w1, w1t, D_, DFF);
    transpose_f2b<<<dim3(D_/32, DFF/32), tb, 0, stream>>>(w2, w2t, DFF, D_);

    ln_kernel<<<NT, 256, 0, stream>>>(x1f, ln2a, ln2b, y2);

    gemm_bt<<<dim3(DFF/BN, NT/BM, 1), 256, 0, stream>>>(
        y2, w1t, w1t, w1t, h_full, h_full, h_full, NT, DFF, D_, 2, b1, nullptr);
    gemm_bt<<<dim3(D_/BN, NT/BM, 1), 256, 0, stream>>>(
        h_full, w2t, w2t, w2t, out, out, out, NT, D_, DFF, 3, b2, x1f);
}

// Round 4
// 697.851 us; speedup vs baseline: 1.1552x; 1.1552x over previous
//
#include <hip/hip_runtime.h>
#include <math.h>

typedef unsigned short u16;
typedef unsigned int u32;
typedef __attribute__((ext_vector_type(4))) unsigned short u16x4;
typedef __attribute__((ext_vector_type(8))) short bf16x8;
typedef __attribute__((ext_vector_type(4))) float f32x4;

#define B_ 4
#define S_ 2048
#define D_ 1024
#define H_ 16
#define NT (B_*S_)
#define DFF 4096

static __device__ __forceinline__ float bf2f(u16 u) {
    return __uint_as_float(((u32)u) << 16);
}
static __device__ __forceinline__ u16 f2bf(float f) {
    u32 u = __float_as_uint(f);
    u32 r = (u + 0x7fffu + ((u >> 16) & 1u)) >> 16;
    return (u16)r;
}
// async 16B/lane global->LDS (LDS dest = wave-uniform base + lane*16)
static __device__ __forceinline__ void gload_lds16(const void* g, void* l) {
    __builtin_amdgcn_global_load_lds(
        (const __attribute__((address_space(1))) void*)g,
        (__attribute__((address_space(3))) void*)l, 16, 0, 0);
}

// ------------------------------------------------- transpose fp32 -> bf16
__global__ void transpose_f2b4(const float* __restrict__ s0, const float* __restrict__ s1,
                               const float* __restrict__ s2, const float* __restrict__ s3,
                               u16* __restrict__ d0, u16* __restrict__ d1,
                               u16* __restrict__ d2, u16* __restrict__ d3,
                               int R, int C) {
    const float* in = s0; u16* out = d0;
    if (blockIdx.z == 1) { in = s1; out = d1; }
    else if (blockIdx.z == 2) { in = s2; out = d2; }
    else if (blockIdx.z == 3) { in = s3; out = d3; }
    __shared__ float t[32][33];
    int c0 = blockIdx.x * 32, r0 = blockIdx.y * 32;
    int x = threadIdx.x, y = threadIdx.y;
    #pragma unroll
    for (int i = 0; i < 4; i++)
        t[y + i*8][x] = in[(long)(r0 + y + i*8) * C + c0 + x];
    __syncthreads();
    #pragma unroll
    for (int i = 0; i < 4; i++)
        out[(long)(c0 + y + i*8) * R + r0 + x] = f2bf(t[x][y + i*8]);
}

__global__ void transpose_f2b(const float* __restrict__ in, u16* __restrict__ out,
                              int R, int C) {
    __shared__ float t[32][33];
    int c0 = blockIdx.x * 32, r0 = blockIdx.y * 32;
    int x = threadIdx.x, y = threadIdx.y;
    #pragma unroll
    for (int i = 0; i < 4; i++)
        t[y + i*8][x] = in[(long)(r0 + y + i*8) * C + c0 + x];
    __syncthreads();
    #pragma unroll
    for (int i = 0; i < 4; i++)
        out[(long)(c0 + y + i*8) * R + r0 + x] = f2bf(t[x][y + i*8]);
}

// V bf16 [B*S][D] -> Vt bf16 [B*H][64][S]. grid (S/32, 2, B*H), block (32,8)
__global__ void transpose_v(const u16* __restrict__ V, u16* __restrict__ Vt) {
    __shared__ u16 t[32][33];
    int z = blockIdx.z; int b = z >> 4, h = z & 15;
    int s0 = blockIdx.x * 32, d0 = blockIdx.y * 32;
    int x = threadIdx.x, y = threadIdx.y;
    const u16* in = V + ((long)b * S_ + s0) * D_ + h * 64 + d0;
    #pragma unroll
    for (int i = 0; i < 4; i++)
        t[y + i*8][x] = in[(long)(y + i*8) * D_ + x];
    __syncthreads();
    u16* out = Vt + ((long)z * 64 + d0) * S_ + s0;
    #pragma unroll
    for (int i = 0; i < 4; i++)
        out[(long)(y + i*8) * S_ + x] = t[x][y + i*8];
}

// ------------------------------------------------- layernorm (fp32 in, bf16 out)
__global__ __launch_bounds__(256) void ln_kernel(
    const float* __restrict__ X, const float* __restrict__ alpha,
    const float* __restrict__ beta, u16* __restrict__ Y) {
    int row = blockIdx.x, tid = threadIdx.x;
    float4 xv = ((const float4*)(X + (long)row * D_))[tid];
    float v[4] = {xv.x, xv.y, xv.z, xv.w};
    float s = 0.f, ss = 0.f;
    #pragma unroll
    for (int i = 0; i < 4; i++) { s += v[i]; ss += v[i]*v[i]; }
    #pragma unroll
    for (int off = 32; off >= 1; off >>= 1) {
        s += __shfl_xor(s, off);
        ss += __shfl_xor(ss, off);
    }
    __shared__ float red[8];
    __shared__ float stats[2];
    int w = tid >> 6;
    if ((tid & 63) == 0) { red[w] = s; red[4 + w] = ss; }
    __syncthreads();
    if (tid == 0) {
        float S = red[0] + red[1] + red[2] + red[3];
        float SS = red[4] + red[5] + red[6] + red[7];
        float mean = S * (1.f / D_);
        float var = SS * (1.f / D_) - mean * mean;
        stats[0] = mean; stats[1] = rsqrtf(var + 1e-5f);
    }
    __syncthreads();
    float mean = stats[0], rstd = stats[1];
    float4 av = ((const float4*)alpha)[tid];
    float4 bv = ((const float4*)beta)[tid];
    u16x4 o;
    o[0] = f2bf((v[0] - mean) * rstd * av.x + bv.x);
    o[1] = f2bf((v[1] - mean) * rstd * av.y + bv.y);
    o[2] = f2bf((v[2] - mean) * rstd * av.z + bv.z);
    o[3] = f2bf((v[3] - mean) * rstd * av.w + bv.w);
    *(u16x4*)(Y + (long)row * D_ + tid * 4) = o;
}

// ------------------------------------------------- GEMM (bf16 A, bf16 B^T)
// BASELINE m97 recipe restored verbatim (R10 post-mortem: 64KB dbuf cost
// occupancy 30->23% and the XCD-chunk swizzle INVERTED default L2 locality,
// FETCH 78->140MB. Default dispatch round-robin already gives each XCD an
// L2-resident B-panel set for these shapes. Do not re-add either.)
#define BM 128
#define BN 128
#define BK 64

__global__ __launch_bounds__(256, 3) void gemm_bt(
    const u16* __restrict__ A,
    const u16* __restrict__ Bt0, const u16* __restrict__ Bt1, const u16* __restrict__ Bt2,
    void* __restrict__ C0, void* __restrict__ C1, void* __restrict__ C2,
    int M, int N, int K, int mode,
    const float* __restrict__ bias, const float* __restrict__ resid) {
    const u16* Bt = Bt0; void* C = C0;
    if (blockIdx.z == 1) { Bt = Bt1; C = C1; }
    else if (blockIdx.z == 2) { Bt = Bt2; C = C2; }

    __shared__ __align__(16) u16 Asm[BM * BK];
    __shared__ __align__(16) u16 Bsm[BN * BK];

    int tid = threadIdx.x;
    int lane = tid & 63, wave = tid >> 6;
    int l15 = lane & 15, quad = lane >> 4;
    int wm = wave & 1, wn = wave >> 1;
    long tm0 = (long)blockIdx.y * BM, tn0 = (long)blockIdx.x * BN;

    int srow = lane >> 3;
    int scol = (lane & 7) * 8;

    f32x4 acc[4][4] = {};

    for (int k0 = 0; k0 < K; k0 += BK) {
        __syncthreads();
        #pragma unroll
        for (int c = 0; c < 4; c++) {
            int chunk = wave * 4 + c;
            int row = chunk * 8 + srow;
            gload_lds16(&A[(tm0 + row) * (long)K + k0 + scol], &Asm[chunk * 512]);
            gload_lds16(&Bt[(tn0 + row) * (long)K + k0 + scol], &Bsm[chunk * 512]);
        }
        __syncthreads();
        #pragma unroll
        for (int ks = 0; ks < 2; ks++) {
            bf16x8 af[4], bfm[4];
            #pragma unroll
            for (int mt = 0; mt < 4; mt++)
                af[mt] = *(const bf16x8*)&Asm[(wm*64 + mt*16 + l15) * BK + ks*32 + quad*8];
            #pragma unroll
            for (int nt = 0; nt < 4; nt++)
                bfm[nt] = *(const bf16x8*)&Bsm[(wn*64 + nt*16 + l15) * BK + ks*32 + quad*8];
            #pragma unroll
            for (int mt = 0; mt < 4; mt++)
                #pragma unroll
                for (int nt = 0; nt < 4; nt++)
                    acc[mt][nt] = __builtin_amdgcn_mfma_f32_16x16x32_bf16(
                        af[mt], bfm[nt], acc[mt][nt], 0, 0, 0);
        }
    }

    #pragma unroll
    for (int mt = 0; mt < 4; mt++) {
        #pragma unroll
        for (int nt = 0; nt < 4; nt++) {
            #pragma unroll
            for (int i = 0; i < 4; i++) {
                long r = tm0 + wm*64 + mt*16 + quad*4 + i;
                long cn = tn0 + wn*64 + nt*16 + l15;
                long idx = r * N + cn;
                float val = acc[mt][nt][i];
                if (mode == 0) {
                    ((u16*)C)[idx] = f2bf(val);
                } else if (mode == 1) {
                    ((float*)C)[idx] = val + resid[idx];
                } else if (mode == 2) {
                    val += bias[cn];
                    val = 0.5f * val * (1.0f + erff(val * 0.70710678118654752f));
                    ((u16*)C)[idx] = f2bf(val);
                } else {
                    ((float*)C)[idx] = val + bias[cn] + resid[idx];
                }
            }
        }
    }
}

// ------------------------------------------------- attention
// R12: split-K across wave pairs, SPILL FIXED. R10's launch_bounds(256,4)
// capped VGPR at 128 < ~150 steady-state liveness -> allocator spilled to
// scratch (VGPR_Count 64, FETCH 25->133MB, WRITE 16->96MB, VALUBusy 2.6%).
// bounds(256,2) restores the 256-cap (old codegen: 88 VGPR); grid still
// gives 4 blocks/CU (LDS 38.9KB*4=156KB fits, VGPR ~100 -> 5 waves/SIMD).
// Fixed-max exp2 softmax makes partials EXACTLY additive over k-tiles (no
// rescale), so waves hk=0/1 take even/odd k-tiles (partition, not
// duplication) -> longest serial k-chain halves (33 -> 17 tiles) AND
// waves/CU doubles (8 -> 16). Merge = 2 barriers + LDS add per tile.
// Head->XCD L2 locality preserved: linear id = x + 64*y, %8 = x%8.
#define LDP 72   // P row stride in u16

__global__ __launch_bounds__(256, 2) void attn_kernel(
    const u16* __restrict__ Q, const u16* __restrict__ Kg, const u16* __restrict__ Vt,
    const int* __restrict__ mask, u16* __restrict__ O) {
    __shared__ __align__(16) u16 Psm[4][32 * LDP];
    __shared__ __align__(16) float Mrg[2][64][40];   // partial o(32)+lacc(8) per lane
    int tid = threadIdx.x;
    int lane = tid & 63, wave = tid >> 6;
    int l15 = lane & 15, quad = lane >> 4;
    int bh = blockIdx.x; int b = bh >> 4, h = bh & 15;
    int pslot = wave >> 1;              // pair slot within block (0..1)
    int hk = wave & 1;                  // k-range half (even/odd k-tiles)
    int j = blockIdx.y * 2 + pslot;     // pair index 0..31
    long tokBase = (long)b * S_;
    const float SCL = 0.125f * 1.4426950408889634f;  // exp2 domain
    const float MMAX = 20.0f;                        // fixed softmax shift

    const bf16x8 ones = {16256,16256,16256,16256,16256,16256,16256,16256}; // bf16 1.0
    u16* Pw = Psm[wave];
    const int* mb = mask + b * S_;

    #pragma unroll
    for (int half = 0; half < 2; half++) {
        int t = half ? (63 - j) : j;   // q-tile index 0..63
        int q0 = t * 32;

        bf16x8 aq[2][2];
        #pragma unroll
        for (int mt = 0; mt < 2; mt++) {
            const u16* qptr = Q + (tokBase + q0 + mt*16 + l15) * D_ + h * 64;
            aq[mt][0] = *(const bf16x8*)(qptr + quad * 8);
            aq[mt][1] = *(const bf16x8*)(qptr + 32 + quad * 8);
        }

        f32x4 o[2][4] = {};
        f32x4 lacc[2] = {};
        int ktiles = t / 2 + 1;

        for (int kt = hk; kt < ktiles; kt += 2) {
            int k0 = kt * 64;
            bf16x8 kb[4][2], vb[4][2];
            #pragma unroll
            for (int nt = 0; nt < 4; nt++) {
                const u16* kp = Kg + (tokBase + k0 + nt*16 + l15) * D_ + h * 64;
                kb[nt][0] = *(const bf16x8*)(kp + quad * 8);
                kb[nt][1] = *(const bf16x8*)(kp + 32 + quad * 8);
            }
            #pragma unroll
            for (int d = 0; d < 4; d++) {
                const u16* vp = Vt + ((long)bh * 64 + d*16 + l15) * S_ + k0;
                vb[d][0] = *(const bf16x8*)(vp + quad * 8);
                vb[d][1] = *(const bf16x8*)(vp + 32 + quad * 8);
            }

            f32x4 s[2][4] = {};
            #pragma unroll
            for (int nt = 0; nt < 4; nt++) {
                s[0][nt] = __builtin_amdgcn_mfma_f32_16x16x32_bf16(aq[0][0], kb[nt][0], s[0][nt], 0,0,0);
                s[0][nt] = __builtin_amdgcn_mfma_f32_16x16x32_bf16(aq[0][1], kb[nt][1], s[0][nt], 0,0,0);
                s[1][nt] = __builtin_amdgcn_mfma_f32_16x16x32_bf16(aq[1][0], kb[nt][0], s[1][nt], 0,0,0);
                s[1][nt] = __builtin_amdgcn_mfma_f32_16x16x32_bf16(aq[1][1], kb[nt][1], s[1][nt], 0,0,0);
            }

            int mk = 0;
            #pragma unroll
            for (int nt = 0; nt < 4; nt++)
                if (mb[k0 + nt*16 + l15] != 0) mk |= (1 << nt);

            #pragma unroll
            for (int mt = 0; mt < 2; mt++) {
                #pragma unroll
                for (int i = 0; i < 4; i++) {
                    int qq = q0 + mt*16 + quad*4 + i;
                    #pragma unroll
                    for (int nt = 0; nt < 4; nt++) {
                        int kc = k0 + nt*16 + l15;
                        float p = exp2f(fmaf(s[mt][nt][i], SCL, -MMAX));
                        p = (kc <= qq && ((mk >> nt) & 1)) ? p : 0.f;
                        Pw[(mt*16 + quad*4 + i) * LDP + nt*16 + l15] = f2bf(p);
                    }
                }
            }
            // same-wave P write -> read ordering (P is wave-private)
            asm volatile("s_waitcnt lgkmcnt(0)" ::: "memory");

            #pragma unroll
            for (int hv = 0; hv < 2; hv++) {
                bf16x8 ap0 = *(const bf16x8*)&Pw[l15 * LDP + hv*32 + quad*8];
                bf16x8 ap1 = *(const bf16x8*)&Pw[(16 + l15) * LDP + hv*32 + quad*8];
                #pragma unroll
                for (int d = 0; d < 4; d++) {
                    o[0][d] = __builtin_amdgcn_mfma_f32_16x16x32_bf16(ap0, vb[d][hv], o[0][d], 0,0,0);
                    o[1][d] = __builtin_amdgcn_mfma_f32_16x16x32_bf16(ap1, vb[d][hv], o[1][d], 0,0,0);
                }
                lacc[0] = __builtin_amdgcn_mfma_f32_16x16x32_bf16(ap0, ones, lacc[0], 0,0,0);
                lacc[1] = __builtin_amdgcn_mfma_f32_16x16x32_bf16(ap1, ones, lacc[1], 0,0,0);
            }
        }

        // merge the two k-halves (partials are additive: fixed MMAX, no rescale)
        if (hk == 1) {
            float* m = &Mrg[pslot][lane][0];
            #pragma unroll
            for (int mt = 0; mt < 2; mt++)
                #pragma unroll
                for (int d = 0; d < 4; d++)
                    *(f32x4*)&m[(mt*4 + d)*4] = o[mt][d];
            *(f32x4*)&m[32] = lacc[0];
            *(f32x4*)&m[36] = lacc[1];
        }
        __syncthreads();
        if (hk == 0) {
            const float* m = &Mrg[pslot][lane][0];
            #pragma unroll
            for (int mt = 0; mt < 2; mt++)
                #pragma unroll
                for (int d = 0; d < 4; d++)
                    o[mt][d] += *(const f32x4*)&m[(mt*4 + d)*4];
            lacc[0] += *(const f32x4*)&m[32];
            lacc[1] += *(const f32x4*)&m[36];

            #pragma unroll
            for (int mt = 0; mt < 2; mt++) {
                #pragma unroll
                for (int i = 0; i < 4; i++) {
                    float inv = 1.f / lacc[mt][i];
                    long r = tokBase + q0 + mt*16 + quad*4 + i;
                    #pragma unroll
                    for (int d = 0; d < 4; d++)
                        O[r * D_ + h*64 + d*16 + l15] = f2bf(o[mt][d][i] * inv);
                }
            }
        }
        __syncthreads();   // protect Mrg reuse by next tile
    }
}

// ------------------------------------------------- launch
extern "C" void kernel_launch(void* const* d_in, const int* in_sizes, int n_in,
                              void* d_out, int out_size, void* d_ws, size_t ws_size,
                              hipStream_t stream) {
    const float* x    = (const float*)d_in[0];
    const int*   am   = (const int*)d_in[1];
    const float* ln1a = (const float*)d_in[2];
    const float* ln1b = (const float*)d_in[3];
    const float* ln2a = (const float*)d_in[4];
    const float* ln2b = (const float*)d_in[5];
    const float* wq   = (const float*)d_in[6];
    const float* wk   = (const float*)d_in[7];
    const float* wv   = (const float*)d_in[8];
    const float* wo   = (const float*)d_in[9];
    const float* w1   = (const float*)d_in[10];
    const float* b1   = (const float*)d_in[11];
    const float* w2   = (const float*)d_in[12];
    const float* b2   = (const float*)d_in[13];
    float* out = (float*)d_out;

    // Workspace: 72 MB, liveness-overlapped 16MB slots.
    char* ws = (char*)d_ws;
    const size_t MB16 = (size_t)16 * 1024 * 1024;
    u16* y1      = (u16*)(ws + 0 * MB16);
    u16* q       = (u16*)(ws + 1 * MB16);
    u16* k       = (u16*)(ws + 2 * MB16);
    u16* v       = (u16*)(ws + 3 * MB16);
    u16* wqt     = (u16*)(ws + 4 * MB16 + 0 * (size_t)D_ * D_ * 2);
    u16* wkt     = (u16*)(ws + 4 * MB16 + 1 * (size_t)D_ * D_ * 2);
    u16* wvt     = (u16*)(ws + 4 * MB16 + 2 * (size_t)D_ * D_ * 2);
    u16* wot     = (u16*)(ws + 4 * MB16 + 3 * (size_t)D_ * D_ * 2);
    u16* y2      = y1;
    u16* w1t     = q;
    u16* w2t     = q + (size_t)D_ * DFF;
    u16* h_full  = k;
    u16* ctx     = v;
    u16*   vt  = (u16*)d_out;                // d_out scratch; dead after attn
    float* x1f = out;

    dim3 tb(32, 8);
    transpose_f2b4<<<dim3(D_/32, D_/32, 4), tb, 0, stream>>>(
        wq, wk, wv, wo, wqt, wkt, wvt, wot, D_, D_);

    ln_kernel<<<NT, 256, 0, stream>>>(x, ln1a, ln1b, y1);

    gemm_bt<<<dim3(D_/BN, NT/BM, 3), 256, 0, stream>>>(
        y1, wqt, wkt, wvt, q, k, v, NT, D_, D_, 0, nullptr, nullptr);

    transpose_v<<<dim3(S_/32, 2, B_*H_), tb, 0, stream>>>(v, vt);

    attn_kernel<<<dim3(B_*H_, 16), 256, 0, stream>>>(q, k, vt, am, ctx);

    gemm_bt<<<dim3(D_/BN, NT/BM, 1), 256, 0, stream>>>(
        ctx, wot, wot, wot, x1f, x1f, x1f, NT, D_, D_, 1, nullptr, x);

    transpose_f2b<<<dim3(DFF/32, D_/32), tb, 0, stream>>>(w1, w1t, D_, DFF);
    transpose_f2b<<<dim3(D_/32, DFF/32), tb, 0, stream>>>(w2, w2t, DFF, D_);

    ln_kernel<<<NT, 256, 0, stream>>>(x1f, ln2a, ln2b, y2);

    gemm_bt<<<dim3(DFF/BN, NT/BM, 1), 256, 0, stream>>>(
        y2, w1t, w1t, w1t, h_full, h_full, h_full, NT, DFF, D_, 2, b1, nullptr);
    gemm_bt<<<dim3(D_/BN, NT/BM, 1), 256, 0, stream>>>(
        h_full, w2t, w2t, w2t, out, out, out, NT, D_, DFF, 3, b2, x1f);
}

// Round 5
// 659.300 us; speedup vs baseline: 1.2228x; 1.0585x over previous
//
#include <hip/hip_runtime.h>
#include <math.h>

typedef unsigned short u16;
typedef unsigned int u32;
typedef __attribute__((ext_vector_type(4))) unsigned short u16x4;
typedef __attribute__((ext_vector_type(8))) short bf16x8;
typedef __attribute__((ext_vector_type(4))) float f32x4;

#define B_ 4
#define S_ 2048
#define D_ 1024
#define H_ 16
#define NT (B_*S_)
#define DFF 4096

static __device__ __forceinline__ float bf2f(u16 u) {
    return __uint_as_float(((u32)u) << 16);
}
static __device__ __forceinline__ u16 f2bf(float f) {
    u32 u = __float_as_uint(f);
    u32 r = (u + 0x7fffu + ((u >> 16) & 1u)) >> 16;
    return (u16)r;
}
// async 16B/lane global->LDS (LDS dest = wave-uniform base + lane*16)
static __device__ __forceinline__ void gload_lds16(const void* g, void* l) {
    __builtin_amdgcn_global_load_lds(
        (const __attribute__((address_space(1))) void*)g,
        (__attribute__((address_space(3))) void*)l, 16, 0, 0);
}

// ------------------------------------------------- transpose fp32 -> bf16
__global__ void transpose_f2b4(const float* __restrict__ s0, const float* __restrict__ s1,
                               const float* __restrict__ s2, const float* __restrict__ s3,
                               u16* __restrict__ d0, u16* __restrict__ d1,
                               u16* __restrict__ d2, u16* __restrict__ d3,
                               int R, int C) {
    const float* in = s0; u16* out = d0;
    if (blockIdx.z == 1) { in = s1; out = d1; }
    else if (blockIdx.z == 2) { in = s2; out = d2; }
    else if (blockIdx.z == 3) { in = s3; out = d3; }
    __shared__ float t[32][33];
    int c0 = blockIdx.x * 32, r0 = blockIdx.y * 32;
    int x = threadIdx.x, y = threadIdx.y;
    #pragma unroll
    for (int i = 0; i < 4; i++)
        t[y + i*8][x] = in[(long)(r0 + y + i*8) * C + c0 + x];
    __syncthreads();
    #pragma unroll
    for (int i = 0; i < 4; i++)
        out[(long)(c0 + y + i*8) * R + r0 + x] = f2bf(t[x][y + i*8]);
}

__global__ void transpose_f2b(const float* __restrict__ in, u16* __restrict__ out,
                              int R, int C) {
    __shared__ float t[32][33];
    int c0 = blockIdx.x * 32, r0 = blockIdx.y * 32;
    int x = threadIdx.x, y = threadIdx.y;
    #pragma unroll
    for (int i = 0; i < 4; i++)
        t[y + i*8][x] = in[(long)(r0 + y + i*8) * C + c0 + x];
    __syncthreads();
    #pragma unroll
    for (int i = 0; i < 4; i++)
        out[(long)(c0 + y + i*8) * R + r0 + x] = f2bf(t[x][y + i*8]);
}

// V bf16 [B*S][D] -> Vt bf16 [B*H][64][S]. grid (S/32, 2, B*H), block (32,8)
__global__ void transpose_v(const u16* __restrict__ V, u16* __restrict__ Vt) {
    __shared__ u16 t[32][33];
    int z = blockIdx.z; int b = z >> 4, h = z & 15;
    int s0 = blockIdx.x * 32, d0 = blockIdx.y * 32;
    int x = threadIdx.x, y = threadIdx.y;
    const u16* in = V + ((long)b * S_ + s0) * D_ + h * 64 + d0;
    #pragma unroll
    for (int i = 0; i < 4; i++)
        t[y + i*8][x] = in[(long)(y + i*8) * D_ + x];
    __syncthreads();
    u16* out = Vt + ((long)z * 64 + d0) * S_ + s0;
    #pragma unroll
    for (int i = 0; i < 4; i++)
        out[(long)(y + i*8) * S_ + x] = t[x][y + i*8];
}

// ------------------------------------------------- layernorm (fp32 in, bf16 out)
__global__ __launch_bounds__(256) void ln_kernel(
    const float* __restrict__ X, const float* __restrict__ alpha,
    const float* __restrict__ beta, u16* __restrict__ Y) {
    int row = blockIdx.x, tid = threadIdx.x;
    float4 xv = ((const float4*)(X + (long)row * D_))[tid];
    float v[4] = {xv.x, xv.y, xv.z, xv.w};
    float s = 0.f, ss = 0.f;
    #pragma unroll
    for (int i = 0; i < 4; i++) { s += v[i]; ss += v[i]*v[i]; }
    #pragma unroll
    for (int off = 32; off >= 1; off >>= 1) {
        s += __shfl_xor(s, off);
        ss += __shfl_xor(ss, off);
    }
    __shared__ float red[8];
    __shared__ float stats[2];
    int w = tid >> 6;
    if ((tid & 63) == 0) { red[w] = s; red[4 + w] = ss; }
    __syncthreads();
    if (tid == 0) {
        float S = red[0] + red[1] + red[2] + red[3];
        float SS = red[4] + red[5] + red[6] + red[7];
        float mean = S * (1.f / D_);
        float var = SS * (1.f / D_) - mean * mean;
        stats[0] = mean; stats[1] = rsqrtf(var + 1e-5f);
    }
    __syncthreads();
    float mean = stats[0], rstd = stats[1];
    float4 av = ((const float4*)alpha)[tid];
    float4 bv = ((const float4*)beta)[tid];
    u16x4 o;
    o[0] = f2bf((v[0] - mean) * rstd * av.x + bv.x);
    o[1] = f2bf((v[1] - mean) * rstd * av.y + bv.y);
    o[2] = f2bf((v[2] - mean) * rstd * av.z + bv.z);
    o[3] = f2bf((v[3] - mean) * rstd * av.w + bv.w);
    *(u16x4*)(Y + (long)row * D_ + tid * 4) = o;
}

// ------------------------------------------------- GEMM (bf16 A, bf16 B^T)
// BASELINE m97 recipe, untouched. (R10 lessons: 64KB dbuf cost occupancy
// 30->23%; XCD-chunk swizzle INVERTED default L2 locality, FETCH 78->140MB.
// Default dispatch round-robin already L2-friendly for these shapes.)
#define BM 128
#define BN 128
#define BK 64

__global__ __launch_bounds__(256, 3) void gemm_bt(
    const u16* __restrict__ A,
    const u16* __restrict__ Bt0, const u16* __restrict__ Bt1, const u16* __restrict__ Bt2,
    void* __restrict__ C0, void* __restrict__ C1, void* __restrict__ C2,
    int M, int N, int K, int mode,
    const float* __restrict__ bias, const float* __restrict__ resid) {
    const u16* Bt = Bt0; void* C = C0;
    if (blockIdx.z == 1) { Bt = Bt1; C = C1; }
    else if (blockIdx.z == 2) { Bt = Bt2; C = C2; }

    __shared__ __align__(16) u16 Asm[BM * BK];
    __shared__ __align__(16) u16 Bsm[BN * BK];

    int tid = threadIdx.x;
    int lane = tid & 63, wave = tid >> 6;
    int l15 = lane & 15, quad = lane >> 4;
    int wm = wave & 1, wn = wave >> 1;
    long tm0 = (long)blockIdx.y * BM, tn0 = (long)blockIdx.x * BN;

    int srow = lane >> 3;
    int scol = (lane & 7) * 8;

    f32x4 acc[4][4] = {};

    for (int k0 = 0; k0 < K; k0 += BK) {
        __syncthreads();
        #pragma unroll
        for (int c = 0; c < 4; c++) {
            int chunk = wave * 4 + c;
            int row = chunk * 8 + srow;
            gload_lds16(&A[(tm0 + row) * (long)K + k0 + scol], &Asm[chunk * 512]);
            gload_lds16(&Bt[(tn0 + row) * (long)K + k0 + scol], &Bsm[chunk * 512]);
        }
        __syncthreads();
        #pragma unroll
        for (int ks = 0; ks < 2; ks++) {
            bf16x8 af[4], bfm[4];
            #pragma unroll
            for (int mt = 0; mt < 4; mt++)
                af[mt] = *(const bf16x8*)&Asm[(wm*64 + mt*16 + l15) * BK + ks*32 + quad*8];
            #pragma unroll
            for (int nt = 0; nt < 4; nt++)
                bfm[nt] = *(const bf16x8*)&Bsm[(wn*64 + nt*16 + l15) * BK + ks*32 + quad*8];
            #pragma unroll
            for (int mt = 0; mt < 4; mt++)
                #pragma unroll
                for (int nt = 0; nt < 4; nt++)
                    acc[mt][nt] = __builtin_amdgcn_mfma_f32_16x16x32_bf16(
                        af[mt], bfm[nt], acc[mt][nt], 0, 0, 0);
        }
    }

    #pragma unroll
    for (int mt = 0; mt < 4; mt++) {
        #pragma unroll
        for (int nt = 0; nt < 4; nt++) {
            #pragma unroll
            for (int i = 0; i < 4; i++) {
                long r = tm0 + wm*64 + mt*16 + quad*4 + i;
                long cn = tn0 + wn*64 + nt*16 + l15;
                long idx = r * N + cn;
                float val = acc[mt][nt][i];
                if (mode == 0) {
                    ((u16*)C)[idx] = f2bf(val);
                } else if (mode == 1) {
                    ((float*)C)[idx] = val + resid[idx];
                } else if (mode == 2) {
                    val += bias[cn];
                    val = 0.5f * val * (1.0f + erff(val * 0.70710678118654752f));
                    ((u16*)C)[idx] = f2bf(val);
                } else {
                    ((float*)C)[idx] = val + bias[cn] + resid[idx];
                }
            }
        }
    }
}

// ------------------------------------------------- attention
// R13: one q-tile per WAVE (baseline: two), grid (64,16) = 1024 blocks,
// LDS = Psm only (18.4 KB). R12 post-mortem: split-K's 38.9KB LDS capped
// co-residency right back at ~2 blocks/CU -> perfect null (dur/occ/VALU
// identical to baseline). This variant raises blocks/CU to 4 (16 waves/CU)
// with the SAME inner loop, zero barriers, no merge. Wave->tile map per
// block y: w0->y, w1->63-y, w2->31-y, w3->32+y (bijective, balanced).
// Head->XCD L2 locality preserved: linear id = x + 64*y, %8 = x%8.
#define LDP 72   // P row stride in u16

__global__ __launch_bounds__(256, 2) void attn_kernel(
    const u16* __restrict__ Q, const u16* __restrict__ Kg, const u16* __restrict__ Vt,
    const int* __restrict__ mask, u16* __restrict__ O) {
    __shared__ __align__(16) u16 Psm[4][32 * LDP];
    int tid = threadIdx.x;
    int lane = tid & 63, wave = tid >> 6;
    int l15 = lane & 15, quad = lane >> 4;
    int bh = blockIdx.x; int b = bh >> 4, h = bh & 15;
    int y = blockIdx.y;                // 0..15
    long tokBase = (long)b * S_;
    const float SCL = 0.125f * 1.4426950408889634f;  // exp2 domain
    const float MMAX = 20.0f;                        // fixed softmax shift

    const bf16x8 ones = {16256,16256,16256,16256,16256,16256,16256,16256}; // bf16 1.0
    u16* Pw = Psm[wave];
    const int* mb = mask + b * S_;

    int t;                             // q-tile 0..63, one per wave
    if (wave == 0)      t = y;
    else if (wave == 1) t = 63 - y;
    else if (wave == 2) t = 31 - y;
    else                t = 32 + y;
    int q0 = t * 32;

    bf16x8 aq[2][2];
    #pragma unroll
    for (int mt = 0; mt < 2; mt++) {
        const u16* qptr = Q + (tokBase + q0 + mt*16 + l15) * D_ + h * 64;
        aq[mt][0] = *(const bf16x8*)(qptr + quad * 8);
        aq[mt][1] = *(const bf16x8*)(qptr + 32 + quad * 8);
    }

    f32x4 o[2][4] = {};
    f32x4 lacc[2] = {};
    int ktiles = t / 2 + 1;

    for (int kt = 0; kt < ktiles; kt++) {
        int k0 = kt * 64;
        bf16x8 kb[4][2], vb[4][2];
        #pragma unroll
        for (int nt = 0; nt < 4; nt++) {
            const u16* kp = Kg + (tokBase + k0 + nt*16 + l15) * D_ + h * 64;
            kb[nt][0] = *(const bf16x8*)(kp + quad * 8);
            kb[nt][1] = *(const bf16x8*)(kp + 32 + quad * 8);
        }
        #pragma unroll
        for (int d = 0; d < 4; d++) {
            const u16* vp = Vt + ((long)bh * 64 + d*16 + l15) * S_ + k0;
            vb[d][0] = *(const bf16x8*)(vp + quad * 8);
            vb[d][1] = *(const bf16x8*)(vp + 32 + quad * 8);
        }

        f32x4 s[2][4] = {};
        #pragma unroll
        for (int nt = 0; nt < 4; nt++) {
            s[0][nt] = __builtin_amdgcn_mfma_f32_16x16x32_bf16(aq[0][0], kb[nt][0], s[0][nt], 0,0,0);
            s[0][nt] = __builtin_amdgcn_mfma_f32_16x16x32_bf16(aq[0][1], kb[nt][1], s[0][nt], 0,0,0);
            s[1][nt] = __builtin_amdgcn_mfma_f32_16x16x32_bf16(aq[1][0], kb[nt][0], s[1][nt], 0,0,0);
            s[1][nt] = __builtin_amdgcn_mfma_f32_16x16x32_bf16(aq[1][1], kb[nt][1], s[1][nt], 0,0,0);
        }

        int mk = 0;
        #pragma unroll
        for (int nt = 0; nt < 4; nt++)
            if (mb[k0 + nt*16 + l15] != 0) mk |= (1 << nt);

        #pragma unroll
        for (int mt = 0; mt < 2; mt++) {
            #pragma unroll
            for (int i = 0; i < 4; i++) {
                int qq = q0 + mt*16 + quad*4 + i;
                #pragma unroll
                for (int nt = 0; nt < 4; nt++) {
                    int kc = k0 + nt*16 + l15;
                    float p = exp2f(fmaf(s[mt][nt][i], SCL, -MMAX));
                    p = (kc <= qq && ((mk >> nt) & 1)) ? p : 0.f;
                    Pw[(mt*16 + quad*4 + i) * LDP + nt*16 + l15] = f2bf(p);
                }
            }
        }
        // same-wave P write -> read ordering (P is wave-private)
        asm volatile("s_waitcnt lgkmcnt(0)" ::: "memory");

        #pragma unroll
        for (int hv = 0; hv < 2; hv++) {
            bf16x8 ap0 = *(const bf16x8*)&Pw[l15 * LDP + hv*32 + quad*8];
            bf16x8 ap1 = *(const bf16x8*)&Pw[(16 + l15) * LDP + hv*32 + quad*8];
            #pragma unroll
            for (int d = 0; d < 4; d++) {
                o[0][d] = __builtin_amdgcn_mfma_f32_16x16x32_bf16(ap0, vb[d][hv], o[0][d], 0,0,0);
                o[1][d] = __builtin_amdgcn_mfma_f32_16x16x32_bf16(ap1, vb[d][hv], o[1][d], 0,0,0);
            }
            lacc[0] = __builtin_amdgcn_mfma_f32_16x16x32_bf16(ap0, ones, lacc[0], 0,0,0);
            lacc[1] = __builtin_amdgcn_mfma_f32_16x16x32_bf16(ap1, ones, lacc[1], 0,0,0);
        }
    }

    #pragma unroll
    for (int mt = 0; mt < 2; mt++) {
        #pragma unroll
        for (int i = 0; i < 4; i++) {
            float inv = 1.f / lacc[mt][i];
            long r = tokBase + q0 + mt*16 + quad*4 + i;
            #pragma unroll
            for (int d = 0; d < 4; d++)
                O[r * D_ + h*64 + d*16 + l15] = f2bf(o[mt][d][i] * inv);
        }
    }
}

// ------------------------------------------------- launch
extern "C" void kernel_launch(void* const* d_in, const int* in_sizes, int n_in,
                              void* d_out, int out_size, void* d_ws, size_t ws_size,
                              hipStream_t stream) {
    const float* x    = (const float*)d_in[0];
    const int*   am   = (const int*)d_in[1];
    const float* ln1a = (const float*)d_in[2];
    const float* ln1b = (const float*)d_in[3];
    const float* ln2a = (const float*)d_in[4];
    const float* ln2b = (const float*)d_in[5];
    const float* wq   = (const float*)d_in[6];
    const float* wk   = (const float*)d_in[7];
    const float* wv   = (const float*)d_in[8];
    const float* wo   = (const float*)d_in[9];
    const float* w1   = (const float*)d_in[10];
    const float* b1   = (const float*)d_in[11];
    const float* w2   = (const float*)d_in[12];
    const float* b2   = (const float*)d_in[13];
    float* out = (float*)d_out;

    // Workspace: 72 MB, liveness-overlapped 16MB slots.
    char* ws = (char*)d_ws;
    const size_t MB16 = (size_t)16 * 1024 * 1024;
    u16* y1      = (u16*)(ws + 0 * MB16);
    u16* q       = (u16*)(ws + 1 * MB16);
    u16* k       = (u16*)(ws + 2 * MB16);
    u16* v       = (u16*)(ws + 3 * MB16);
    u16* wqt     = (u16*)(ws + 4 * MB16 + 0 * (size_t)D_ * D_ * 2);
    u16* wkt     = (u16*)(ws + 4 * MB16 + 1 * (size_t)D_ * D_ * 2);
    u16* wvt     = (u16*)(ws + 4 * MB16 + 2 * (size_t)D_ * D_ * 2);
    u16* wot     = (u16*)(ws + 4 * MB16 + 3 * (size_t)D_ * D_ * 2);
    u16* y2      = y1;
    u16* w1t     = q;
    u16* w2t     = q + (size_t)D_ * DFF;
    u16* h_full  = k;
    u16* ctx     = v;
    u16*   vt  = (u16*)d_out;                // d_out scratch; dead after attn
    float* x1f = out;

    dim3 tb(32, 8);
    transpose_f2b4<<<dim3(D_/32, D_/32, 4), tb, 0, stream>>>(
        wq, wk, wv, wo, wqt, wkt, wvt, wot, D_, D_);

    ln_kernel<<<NT, 256, 0, stream>>>(x, ln1a, ln1b, y1);

    gemm_bt<<<dim3(D_/BN, NT/BM, 3), 256, 0, stream>>>(
        y1, wqt, wkt, wvt, q, k, v, NT, D_, D_, 0, nullptr, nullptr);

    transpose_v<<<dim3(S_/32, 2, B_*H_), tb, 0, stream>>>(v, vt);

    attn_kernel<<<dim3(B_*H_, 16), 256, 0, stream>>>(q, k, vt, am, ctx);

    gemm_bt<<<dim3(D_/BN, NT/BM, 1), 256, 0, stream>>>(
        ctx, wot, wot, wot, x1f, x1f, x1f, NT, D_, D_, 1, nullptr, x);

    transpose_f2b<<<dim3(DFF/32, D_/32), tb, 0, stream>>>(w1, w1t, D_, DFF);
    transpose_f2b<<<dim3(D_/32, DFF/32), tb, 0, stream>>>(w2, w2t, DFF, D_);

    ln_kernel<<<NT, 256, 0, stream>>>(x1f, ln2a, ln2b, y2);

    gemm_bt<<<dim3(DFF/BN, NT/BM, 1), 256, 0, stream>>>(
        y2, w1t, w1t, w1t, h_full, h_full, h_full, NT, DFF, D_, 2, b1, nullptr);
    gemm_bt<<<dim3(D_/BN, NT/BM, 1), 256, 0, stream>>>(
        h_full, w2t, w2t, w2t, out, out, out, NT, D_, DFF, 3, b2, x1f);
}